// Round 7
// baseline (142.292 us; speedup 1.0000x reference)
//
#include <hip/hip_runtime.h>
#include <hip/hip_fp16.h>

constexpr int B    = 4;
constexpr int CIN  = 192;
constexpr int COUT = 192;
constexpr int NN   = 16384;
constexpr int KK   = 16;
constexpr int NG   = 4;    // groups
constexpr int GIN  = 48;   // fan_in per group
constexpr int GOUT = 48;   // out channels per group
constexpr int NT   = 64;   // nodes per block: 1024 blocks = 4/CU (proven geometry)
constexpr int TPB  = 192;  // 3 waves: 2 gather + 1 GEMM
constexpr int IST  = 20;   // idx_lds row stride (pad 16->20, 16B-aligned)
constexpr int HST  = 52;   // h_lds row stride  (pad 48->52, 16B-aligned)

// ---------------------------------------------------------------------------
// Kernel 1: transpose + fp16 convert (unchanged, ~7.5 us).
// ---------------------------------------------------------------------------
__global__ __launch_bounds__(256) void transpose_h(const float* __restrict__ x,
                                                   __half* __restrict__ xh) {
    __shared__ float tile[32][33];
    const int b  = blockIdx.z;
    const int n0 = blockIdx.x * 32;
    const int c0 = blockIdx.y * 32;
    const int tx = threadIdx.x;
    const int ty = threadIdx.y;
    const float* xb  = x  + (size_t)b * CIN * NN;
    __half*      xhb = xh + (size_t)b * NN * CIN;
#pragma unroll
    for (int i = 0; i < 32; i += 8)
        tile[ty + i][tx] = xb[(size_t)(c0 + ty + i) * NN + (n0 + tx)];
    __syncthreads();
#pragma unroll
    for (int i = 0; i < 32; i += 8) {
        const int c = c0 + tx, n = n0 + ty + i;
        xhb[((size_t)(c / GIN) * NN + n) * GIN + (c % GIN)] =
            __float2half(tile[tx][ty + i]);
    }
}

__device__ __forceinline__ void cvt8(uint4 u, float4& lo, float4& hi) {
    const __half2* h = (const __half2*)&u;
    const float2 f0 = __half22float2(h[0]), f1 = __half22float2(h[1]);
    const float2 f2 = __half22float2(h[2]), f3 = __half22float2(h[3]);
    lo = make_float4(f0.x, f0.y, f1.x, f1.y);
    hi = make_float4(f2.x, f2.y, f3.x, f3.y);
}
__device__ __forceinline__ void acc8(float4& lo, float4& hi, uint4 u) {
    float4 l, h; cvt8(u, l, h);
    lo.x += l.x; lo.y += l.y; lo.z += l.z; lo.w += l.w;
    hi.x += h.x; hi.y += h.y; hi.z += h.z; hi.w += h.w;
}
// one fp16 packed add level (v_pk_add_f16): exact inputs, single rounding
__device__ __forceinline__ uint4 pair8(uint4 a, uint4 b) {
    const __half2* ha = (const __half2*)&a;
    const __half2* hb = (const __half2*)&b;
    uint4 o;
    __half2* ho = (__half2*)&o;
    ho[0] = __hadd2(ha[0], hb[0]);
    ho[1] = __hadd2(ha[1], hb[1]);
    ho[2] = __hadd2(ha[2], hb[2]);
    ho[3] = __hadd2(ha[3], hb[3]);
    return o;
}

// one gather task: node-row i, slot e (16 B of the 96 B slice).
// 17 loads -> fp16 pair level -> fp32 tree -> +(1+eps)*self -> h row.
// Batch is consumed IMMEDIATELY (short liveness, no cross-phase holding —
// the R6 spill lesson).  At the TA wall (1 lane-addr/cy/CU) issue order
// inside the task is irrelevant; only total lane-address count matters.
__device__ __forceinline__ void gather_task(const uint4* __restrict__ xg,
                                            const int* __restrict__ idx_lds,
                                            int n0, int task, float e1,
                                            float* __restrict__ dst) {
    const int i = task / 6;
    const int e = task - i * 6;
    const int4* ip = (const int4*)(idx_lds + i * IST);
    const int4 ja = ip[0], jb = ip[1], jc = ip[2], jd = ip[3];
    const uint4 us  = xg[(n0 + i) * 6 + e];
    const uint4 u0  = xg[ja.x * 6 + e], u1  = xg[ja.y * 6 + e];
    const uint4 u2  = xg[ja.z * 6 + e], u3  = xg[ja.w * 6 + e];
    const uint4 u4  = xg[jb.x * 6 + e], u5  = xg[jb.y * 6 + e];
    const uint4 u6  = xg[jb.z * 6 + e], u7  = xg[jb.w * 6 + e];
    const uint4 u8  = xg[jc.x * 6 + e], u9  = xg[jc.y * 6 + e];
    const uint4 u10 = xg[jc.z * 6 + e], u11 = xg[jc.w * 6 + e];
    const uint4 u12 = xg[jd.x * 6 + e], u13 = xg[jd.y * 6 + e];
    const uint4 u14 = xg[jd.z * 6 + e], u15 = xg[jd.w * 6 + e];
    const uint4 p0 = pair8(u0,  u1),  p1 = pair8(u2,  u3);
    const uint4 p2 = pair8(u4,  u5),  p3 = pair8(u6,  u7);
    const uint4 p4 = pair8(u8,  u9),  p5 = pair8(u10, u11);
    const uint4 p6 = pair8(u12, u13), p7 = pair8(u14, u15);
    float4 aLo, aHi; cvt8(p0, aLo, aHi);
    acc8(aLo, aHi, p1); acc8(aLo, aHi, p2); acc8(aLo, aHi, p3);
    acc8(aLo, aHi, p4); acc8(aLo, aHi, p5); acc8(aLo, aHi, p6);
    acc8(aLo, aHi, p7);
    float4 sLo, sHi; cvt8(us, sLo, sHi);
    float4 lo, hi;
    lo.x = fmaf(e1, sLo.x, aLo.x); lo.y = fmaf(e1, sLo.y, aLo.y);
    lo.z = fmaf(e1, sLo.z, aLo.z); lo.w = fmaf(e1, sLo.w, aLo.w);
    hi.x = fmaf(e1, sHi.x, aHi.x); hi.y = fmaf(e1, sHi.y, aHi.y);
    hi.z = fmaf(e1, sHi.z, aHi.z); hi.w = fmaf(e1, sHi.w, aHi.w);
    float4* hp = (float4*)(dst + i * HST + e * 8);
    hp[0] = lo;
    hp[1] = hi;
}

// ---------------------------------------------------------------------------
// Kernel 2: producer/consumer wave specialization.
//   waves 0-1 (128 lanes): gather.  384 tasks/group (64 nodes x 6 slots),
//     3 tasks per lane.  No weight registers EVER in these waves.
//   wave 2 (48 active lanes): full 48x64 grouped GEMM.  lane = co; h rows
//     read broadcast from LDS (lane-invariant address, conflict-free);
//     only these 48 lanes load wv -> weight TA traffic drops 4x vs R5
//     (15.4 us -> 3.8 us of the per-CU TA budget).
//   Double-buffered h_lds; gather produces h[g+1] while GEMM consumes h[g];
//   ONE barrier per group (wave-uniform role branch, equal barrier counts).
// ---------------------------------------------------------------------------
__global__ __launch_bounds__(TPB, 3) void gin_fused(const __half* __restrict__ xh,
                                                    const int*   __restrict__ idx,
                                                    const float* __restrict__ w,
                                                    const float* __restrict__ bias,
                                                    const float* __restrict__ eps,
                                                    float* __restrict__ out) {
    __shared__ __align__(16) float h_lds[2][NT * HST];  // 26.6 KB
    __shared__ __align__(16) int   idx_lds[NT * IST];   // 5.1 KB

    const int tid = threadIdx.x;
    const int blk = blockIdx.x;
    const int b   = blk & 3;
    const int n0  = (blk >> 2) * NT;

    const float e1 = 1.0f + eps[0];

    {
        const int* gi = idx + ((size_t)b * NN + n0) * KK;
        for (int t = tid; t < NT * KK; t += TPB)
            idx_lds[(t >> 4) * IST + (t & 15)] = gi[t];
    }
    __syncthreads();

    const __half* xb = xh + (size_t)b * NN * CIN;
    float*        ob = out + (size_t)b * COUT * NN;

    if (tid < 128) {
        // ================= gather role (waves 0,1) =================
        // prologue: group 0 -> h[0]
        {
            const uint4* xg = (const uint4*)xb;
#pragma unroll
            for (int r = 0; r < 3; ++r)
                gather_task(xg, idx_lds, n0, r * 128 + tid, e1, h_lds[0]);
        }
        __syncthreads();
#pragma unroll
        for (int g = 0; g < NG; ++g) {
            if (g < NG - 1) {
                const uint4* xg =
                    (const uint4*)(xb + (size_t)(g + 1) * NN * GIN);
#pragma unroll
                for (int r = 0; r < 3; ++r)
                    gather_task(xg, idx_lds, n0, r * 128 + tid, e1,
                                h_lds[(g + 1) & 1]);
            }
            __syncthreads();
        }
    } else {
        // ================= GEMM role (wave 2) =================
        const int co = tid - 128;          // 0..63; active if < 48
        __syncthreads();                   // match gather prologue barrier
#pragma unroll
        for (int g = 0; g < NG; ++g) {
            if (co < GOUT) {
                float4 wv[12];
                const float* wr = w + (size_t)(g * GOUT + co) * GIN;
#pragma unroll
                for (int ii = 0; ii < 12; ++ii) wv[ii] = ((const float4*)wr)[ii];
                const float bi = bias[g * GOUT + co];
                const float* hbuf = h_lds[g & 1];
                float* orow = ob + (size_t)(g * GOUT + co) * NN + n0;
#pragma unroll
                for (int i4 = 0; i4 < 16; ++i4) {
                    float av[4];
#pragma unroll
                    for (int t = 0; t < 4; ++t) {
                        const float* hr = hbuf + (i4 * 4 + t) * HST;
                        float s = bi;
#pragma unroll
                        for (int ii = 0; ii < 12; ++ii) {
                            const float4 hv = ((const float4*)hr)[ii];
                            s = fmaf(wv[ii].x, hv.x, s);
                            s = fmaf(wv[ii].y, hv.y, s);
                            s = fmaf(wv[ii].z, hv.z, s);
                            s = fmaf(wv[ii].w, hv.w, s);
                        }
                        av[t] = fmaxf(s, 0.0f);
                    }
                    ((float4*)orow)[i4] = make_float4(av[0], av[1], av[2], av[3]);
                }
            }
            __syncthreads();
        }
    }
}

// ---------------------------------------------------------------------------
extern "C" void kernel_launch(void* const* d_in, const int* in_sizes, int n_in,
                              void* d_out, int out_size, void* d_ws, size_t ws_size,
                              hipStream_t stream) {
    const float* x      = (const float*)d_in[0];
    const int*   edge   = (const int*)  d_in[1];  // edge_index[0] = first half
    const float* weight = (const float*)d_in[2];
    const float* bias   = (const float*)d_in[3];
    const float* eps    = (const float*)d_in[4];
    float*       out    = (float*)d_out;
    __half*      xh     = (__half*)d_ws;          // B*N*192 halfs = 25.2 MB

    dim3 tblk(32, 8);
    dim3 tgrd(NN / 32, CIN / 32, B);
    transpose_h<<<tgrd, tblk, 0, stream>>>(x, xh);

    gin_fused<<<B * (NN / NT), TPB, 0, stream>>>(xh, edge, weight, bias, eps, out);
}

// Round 8
// 75.628 us; speedup vs baseline: 1.8815x; 1.8815x over previous
//
#include <hip/hip_runtime.h>
#include <hip/hip_fp16.h>

constexpr int B    = 4;
constexpr int CIN  = 192;
constexpr int COUT = 192;
constexpr int NN   = 16384;
constexpr int KK   = 16;
constexpr int NG   = 4;    // groups
constexpr int GIN  = 48;   // fan_in per group
constexpr int GOUT = 48;   // out channels per group
constexpr int NT   = 64;   // nodes per block: 1024 blocks = 4/CU (proven geometry)
constexpr int TPB  = 192;
constexpr int IST  = 20;   // idx_lds row stride (pad 16->20, 16B-aligned)
constexpr int HST  = 52;   // h_lds row stride  (pad 48->52, 16B-aligned)
constexpr int WST  = 52;   // w_lds row stride  (pad 48->52, 16B-aligned)

// ---------------------------------------------------------------------------
// Kernel 1: transpose + fp16 convert (unchanged, ~7.5 us).
// ---------------------------------------------------------------------------
__global__ __launch_bounds__(256) void transpose_h(const float* __restrict__ x,
                                                   __half* __restrict__ xh) {
    __shared__ float tile[32][33];
    const int b  = blockIdx.z;
    const int n0 = blockIdx.x * 32;
    const int c0 = blockIdx.y * 32;
    const int tx = threadIdx.x;
    const int ty = threadIdx.y;
    const float* xb  = x  + (size_t)b * CIN * NN;
    __half*      xhb = xh + (size_t)b * NN * CIN;
#pragma unroll
    for (int i = 0; i < 32; i += 8)
        tile[ty + i][tx] = xb[(size_t)(c0 + ty + i) * NN + (n0 + tx)];
    __syncthreads();
#pragma unroll
    for (int i = 0; i < 32; i += 8) {
        const int c = c0 + tx, n = n0 + ty + i;
        xhb[((size_t)(c / GIN) * NN + n) * GIN + (c % GIN)] =
            __float2half(tile[tx][ty + i]);
    }
}

__device__ __forceinline__ void cvt8(uint4 u, float4& lo, float4& hi) {
    const __half2* h = (const __half2*)&u;
    const float2 f0 = __half22float2(h[0]), f1 = __half22float2(h[1]);
    const float2 f2 = __half22float2(h[2]), f3 = __half22float2(h[3]);
    lo = make_float4(f0.x, f0.y, f1.x, f1.y);
    hi = make_float4(f2.x, f2.y, f3.x, f3.y);
}
__device__ __forceinline__ void acc8(float4& lo, float4& hi, uint4 u) {
    float4 l, h; cvt8(u, l, h);
    lo.x += l.x; lo.y += l.y; lo.z += l.z; lo.w += l.w;
    hi.x += h.x; hi.y += h.y; hi.z += h.z; hi.w += h.w;
}

// ---------------------------------------------------------------------------
// Kernel 2: R5 structure (proven 70.5 us) with ONE change: weights (and bias)
// are staged into LDS once per block instead of loaded by every thread.
// TA model (1 lane-addr/cy/CU): R5 spent 15.4 us of the per-CU vector-memory
// address budget on redundant wv loads (each of 196608 threads x 12 float4 x
// 4 groups).  Staged: 576 float4 per block per group = 0.59M lane-addrs
// (~1 us).  GEMM reads wv from LDS -> even compiler rematerialization stays
// off the TA path.  Everything else byte-identical to R5.
// ---------------------------------------------------------------------------
__global__ __launch_bounds__(TPB, 3) void gin_fused(const __half* __restrict__ xh,
                                                    const int*   __restrict__ idx,
                                                    const float* __restrict__ w,
                                                    const float* __restrict__ bias,
                                                    const float* __restrict__ eps,
                                                    float* __restrict__ out) {
    __shared__ __align__(16) float h_lds[NT * HST];    // 13.3 KB
    __shared__ __align__(16) float w_lds[GOUT * WST];  // 10.0 KB
    __shared__ __align__(16) int   idx_lds[NT * IST];  // 5.1 KB
    __shared__ float b_lds[COUT];                      // 0.75 KB

    const int tid = threadIdx.x;
    const int blk = blockIdx.x;
    const int b   = blk & 3;
    const int n0  = (blk >> 2) * NT;

    const float e1 = 1.0f + eps[0];

    {
        const int* gi = idx + ((size_t)b * NN + n0) * KK;
        for (int t = tid; t < NT * KK; t += TPB)
            idx_lds[(t >> 4) * IST + (t & 15)] = gi[t];
        b_lds[tid] = bias[tid];                        // TPB==COUT==192
    }

    // gather map: 6 lanes x uint4 (8 fp16 ch) cover one 96 B node-slice
    const int e    = tid % 6;    // 0..5
    const int isub = tid / 6;    // 0..31
    // gemm map
    const int co   = tid % GOUT; // 0..47
    const int q    = tid / GOUT; // 0..3

    const __half* xb = xh + (size_t)b * NN * CIN;
    float*        ob = out + (size_t)b * COUT * NN;

    __syncthreads();

    for (int g = 0; g < NG; ++g) {
        // ---- stage w(g) -> LDS (3 float4 loads + writes per thread) ----
        // Overwrite of w_lds is safe: previous group's GEMM retired at the
        // end-of-group barrier.  Visibility: the post-gather barrier below.
        {
            const float* wg = w + (size_t)g * GOUT * GIN;
#pragma unroll
            for (int t = 0; t < 3; ++t) {
                const int  idx4 = tid + t * TPB;       // 0..575
                const int  row  = idx4 / 12, slot = idx4 % 12;
                const float4 v = ((const float4*)(wg + (size_t)row * GIN))[slot];
                ((float4*)(w_lds + row * WST))[slot] = v;
            }
        }

        // ---- Phase 1: fp16 gather + fp32 sum (R5 body, unchanged) ----
        const uint4* xg = (const uint4*)(xb + (size_t)g * NN * GIN);
#pragma unroll
        for (int r = 0; r < 2; ++r) {
            const int i = isub + 32 * r;
            const int4* ip = (const int4*)(idx_lds + i * IST);
            const int4 ja = ip[0], jb = ip[1], jc = ip[2], jd = ip[3];
            const uint4 us  = xg[(n0 + i) * 6 + e];
            const uint4 u0  = xg[ja.x * 6 + e], u1  = xg[ja.y * 6 + e];
            const uint4 u2  = xg[ja.z * 6 + e], u3  = xg[ja.w * 6 + e];
            const uint4 u4  = xg[jb.x * 6 + e], u5  = xg[jb.y * 6 + e];
            const uint4 u6  = xg[jb.z * 6 + e], u7  = xg[jb.w * 6 + e];
            const uint4 u8  = xg[jc.x * 6 + e], u9  = xg[jc.y * 6 + e];
            const uint4 u10 = xg[jc.z * 6 + e], u11 = xg[jc.w * 6 + e];
            const uint4 u12 = xg[jd.x * 6 + e], u13 = xg[jd.y * 6 + e];
            const uint4 u14 = xg[jd.z * 6 + e], u15 = xg[jd.w * 6 + e];
            // two independent accumulation chains (even/odd neighbors)
            float4 aLo, aHi, bLo, bHi;
            cvt8(u0, aLo, aHi);      cvt8(u1, bLo, bHi);
            acc8(aLo, aHi, u2);      acc8(bLo, bHi, u3);
            acc8(aLo, aHi, u4);      acc8(bLo, bHi, u5);
            acc8(aLo, aHi, u6);      acc8(bLo, bHi, u7);
            acc8(aLo, aHi, u8);      acc8(bLo, bHi, u9);
            acc8(aLo, aHi, u10);     acc8(bLo, bHi, u11);
            acc8(aLo, aHi, u12);     acc8(bLo, bHi, u13);
            acc8(aLo, aHi, u14);     acc8(bLo, bHi, u15);
            float4 sLo, sHi; cvt8(us, sLo, sHi);
            float4 lo, hi;
            lo.x = fmaf(e1, sLo.x, aLo.x + bLo.x);
            lo.y = fmaf(e1, sLo.y, aLo.y + bLo.y);
            lo.z = fmaf(e1, sLo.z, aLo.z + bLo.z);
            lo.w = fmaf(e1, sLo.w, aLo.w + bLo.w);
            hi.x = fmaf(e1, sHi.x, aHi.x + bHi.x);
            hi.y = fmaf(e1, sHi.y, aHi.y + bHi.y);
            hi.z = fmaf(e1, sHi.z, aHi.z + bHi.z);
            hi.w = fmaf(e1, sHi.w, aHi.w + bHi.w);
            float4* hp = (float4*)(h_lds + i * HST + e * 8);
            hp[0] = lo;
            hp[1] = hi;
        }
        __syncthreads();
        __builtin_amdgcn_sched_barrier(0);

        // ---- Phase 2: grouped GEMM + ReLU + direct store (wv from LDS) ----
        float4 wv[12];
        {
            const float* wr = w_lds + co * WST;
#pragma unroll
            for (int ii = 0; ii < 12; ++ii) wv[ii] = ((const float4*)wr)[ii];
        }
        const float bi = b_lds[g * GOUT + co];
        float* orow = ob + (size_t)(g * GOUT + co) * NN + n0 + q * 16;
#pragma unroll
        for (int i4 = 0; i4 < 4; ++i4) {
            float av[4];
#pragma unroll
            for (int t = 0; t < 4; ++t) {
                const float* hr = h_lds + (q * 16 + i4 * 4 + t) * HST;
                float s = bi;
#pragma unroll
                for (int ii = 0; ii < 12; ++ii) {
                    const float4 hv = ((const float4*)hr)[ii];
                    s = fmaf(wv[ii].x, hv.x, s);
                    s = fmaf(wv[ii].y, hv.y, s);
                    s = fmaf(wv[ii].z, hv.z, s);
                    s = fmaf(wv[ii].w, hv.w, s);
                }
                av[t] = fmaxf(s, 0.0f);
            }
            ((float4*)orow)[i4] = make_float4(av[0], av[1], av[2], av[3]);
        }
        __syncthreads();   // h_lds/w_lds safe to overwrite next group
    }
}

// ---------------------------------------------------------------------------
extern "C" void kernel_launch(void* const* d_in, const int* in_sizes, int n_in,
                              void* d_out, int out_size, void* d_ws, size_t ws_size,
                              hipStream_t stream) {
    const float* x      = (const float*)d_in[0];
    const int*   edge   = (const int*)  d_in[1];  // edge_index[0] = first half
    const float* weight = (const float*)d_in[2];
    const float* bias   = (const float*)d_in[3];
    const float* eps    = (const float*)d_in[4];
    float*       out    = (float*)d_out;
    __half*      xh     = (__half*)d_ws;          // B*N*192 halfs = 25.2 MB

    dim3 tblk(32, 8);
    dim3 tgrd(NN / 32, CIN / 32, B);
    transpose_h<<<tgrd, tblk, 0, stream>>>(x, xh);

    gin_fused<<<B * (NN / NT), TPB, 0, stream>>>(xh, edge, weight, bias, eps, out);
}

// Round 9
// 64.896 us; speedup vs baseline: 2.1926x; 1.1654x over previous
//
#include <hip/hip_runtime.h>
#include <hip/hip_fp16.h>

constexpr int B    = 4;
constexpr int CIN  = 192;
constexpr int COUT = 192;
constexpr int NN   = 16384;
constexpr int KK   = 16;
constexpr int NG   = 4;    // groups
constexpr int GIN  = 48;   // fan_in per group
constexpr int GOUT = 48;   // out channels per group
constexpr int NT   = 64;   // nodes per block: 1024 blocks = 4/CU (proven geometry)
constexpr int TPB  = 192;
constexpr int IST  = 20;   // idx_lds row stride (pad 16->20, 16B-aligned)
constexpr int HST  = 52;   // h_lds row stride  (pad 48->52, 16B-aligned)
constexpr int WST  = 52;   // w_lds row stride  (pad 48->52, 16B-aligned)

// ---------------------------------------------------------------------------
// Kernel 1: transpose + fp16 convert (unchanged, ~6 us).
// ---------------------------------------------------------------------------
__global__ __launch_bounds__(256) void transpose_h(const float* __restrict__ x,
                                                   __half* __restrict__ xh) {
    __shared__ float tile[32][33];
    const int b  = blockIdx.z;
    const int n0 = blockIdx.x * 32;
    const int c0 = blockIdx.y * 32;
    const int tx = threadIdx.x;
    const int ty = threadIdx.y;
    const float* xb  = x  + (size_t)b * CIN * NN;
    __half*      xhb = xh + (size_t)b * NN * CIN;
#pragma unroll
    for (int i = 0; i < 32; i += 8)
        tile[ty + i][tx] = xb[(size_t)(c0 + ty + i) * NN + (n0 + tx)];
    __syncthreads();
#pragma unroll
    for (int i = 0; i < 32; i += 8) {
        const int c = c0 + tx, n = n0 + ty + i;
        xhb[((size_t)(c / GIN) * NN + n) * GIN + (c % GIN)] =
            __float2half(tile[tx][ty + i]);
    }
}

__device__ __forceinline__ void cvt8(uint4 u, float4& lo, float4& hi) {
    const __half2* h = (const __half2*)&u;
    const float2 f0 = __half22float2(h[0]), f1 = __half22float2(h[1]);
    const float2 f2 = __half22float2(h[2]), f3 = __half22float2(h[3]);
    lo = make_float4(f0.x, f0.y, f1.x, f1.y);
    hi = make_float4(f2.x, f2.y, f3.x, f3.y);
}
__device__ __forceinline__ void acc8(float4& lo, float4& hi, uint4 u) {
    float4 l, h; cvt8(u, l, h);
    lo.x += l.x; lo.y += l.y; lo.z += l.z; lo.w += l.w;
    hi.x += h.x; hi.y += h.y; hi.z += h.z; hi.w += h.w;
}

// ---------------------------------------------------------------------------
// Kernel 2: R8 gather (proven, TA-wall 43.5 us) + REMAPPED GEMM/store phase.
// R8's counters showed WRITE_SIZE = 2x out size: direct 16-B fragment stores
// from different waves left partial-dirty 128-B lines that L2 wrote back
// twice.  New mapping: thread (e2=tid%16, r2=tid/16) computes channels
// {r2+12m} x nodes [4e2,4e2+4) -> each store inst = 16 consecutive lanes x
// 16 B = one FULL 256-B channel row.  h rows reused across the 4 channels
// (96 ds_reads/thread/group vs 204).  h_lds rows permuted sigma(i) =
// (i&3)*16 + (i>>2) so the GEMM's 16 per-inst row addresses are consecutive
// rows (bank stride 20 mod 32 -> 2-way, free) instead of 8-way conflicted.
// ---------------------------------------------------------------------------
__global__ __launch_bounds__(TPB, 3) void gin_fused(const __half* __restrict__ xh,
                                                    const int*   __restrict__ idx,
                                                    const float* __restrict__ w,
                                                    const float* __restrict__ bias,
                                                    const float* __restrict__ eps,
                                                    float* __restrict__ out) {
    __shared__ __align__(16) float h_lds[NT * HST];    // 13.3 KB
    __shared__ __align__(16) float w_lds[GOUT * WST];  // 10.0 KB
    __shared__ __align__(16) int   idx_lds[NT * IST];  // 5.1 KB
    __shared__ float b_lds[COUT];                      // 0.75 KB

    const int tid = threadIdx.x;
    const int blk = blockIdx.x;
    const int b   = blk & 3;
    const int n0  = (blk >> 2) * NT;

    const float e1 = 1.0f + eps[0];

    {
        const int* gi = idx + ((size_t)b * NN + n0) * KK;
        for (int t = tid; t < NT * KK; t += TPB)
            idx_lds[(t >> 4) * IST + (t & 15)] = gi[t];
        b_lds[tid] = bias[tid];                        // TPB==COUT==192
    }

    // gather map: 6 lanes x uint4 (8 fp16 ch) cover one 96 B node-slice
    const int e    = tid % 6;    // 0..5
    const int isub = tid / 6;    // 0..31
    // gemm map (coalesced-store form)
    const int e2   = tid & 15;   // node-quad: nodes 4*e2 .. 4*e2+3
    const int r2   = tid >> 4;   // 0..11: channels r2, r2+12, r2+24, r2+36

    const __half* xb = xh + (size_t)b * NN * CIN;
    float*        ob = out + (size_t)b * COUT * NN;

    __syncthreads();

    for (int g = 0; g < NG; ++g) {
        // ---- stage w(g) -> LDS (unchanged from R8) ----
        {
            const float* wg = w + (size_t)g * GOUT * GIN;
#pragma unroll
            for (int t = 0; t < 3; ++t) {
                const int  idx4 = tid + t * TPB;       // 0..575
                const int  row  = idx4 / 12, slot = idx4 % 12;
                const float4 v = ((const float4*)(wg + (size_t)row * GIN))[slot];
                ((float4*)(w_lds + row * WST))[slot] = v;
            }
        }

        // ---- Phase 1: fp16 gather + fp32 sum (unchanged except sigma row) ----
        const uint4* xg = (const uint4*)(xb + (size_t)g * NN * GIN);
#pragma unroll
        for (int r = 0; r < 2; ++r) {
            const int i = isub + 32 * r;
            const int4* ip = (const int4*)(idx_lds + i * IST);
            const int4 ja = ip[0], jb = ip[1], jc = ip[2], jd = ip[3];
            const uint4 us  = xg[(n0 + i) * 6 + e];
            const uint4 u0  = xg[ja.x * 6 + e], u1  = xg[ja.y * 6 + e];
            const uint4 u2  = xg[ja.z * 6 + e], u3  = xg[ja.w * 6 + e];
            const uint4 u4  = xg[jb.x * 6 + e], u5  = xg[jb.y * 6 + e];
            const uint4 u6  = xg[jb.z * 6 + e], u7  = xg[jb.w * 6 + e];
            const uint4 u8  = xg[jc.x * 6 + e], u9  = xg[jc.y * 6 + e];
            const uint4 u10 = xg[jc.z * 6 + e], u11 = xg[jc.w * 6 + e];
            const uint4 u12 = xg[jd.x * 6 + e], u13 = xg[jd.y * 6 + e];
            const uint4 u14 = xg[jd.z * 6 + e], u15 = xg[jd.w * 6 + e];
            // two independent accumulation chains (even/odd neighbors)
            float4 aLo, aHi, bLo, bHi;
            cvt8(u0, aLo, aHi);      cvt8(u1, bLo, bHi);
            acc8(aLo, aHi, u2);      acc8(bLo, bHi, u3);
            acc8(aLo, aHi, u4);      acc8(bLo, bHi, u5);
            acc8(aLo, aHi, u6);      acc8(bLo, bHi, u7);
            acc8(aLo, aHi, u8);      acc8(bLo, bHi, u9);
            acc8(aLo, aHi, u10);     acc8(bLo, bHi, u11);
            acc8(aLo, aHi, u12);     acc8(bLo, bHi, u13);
            acc8(aLo, aHi, u14);     acc8(bLo, bHi, u15);
            float4 sLo, sHi; cvt8(us, sLo, sHi);
            float4 lo, hi;
            lo.x = fmaf(e1, sLo.x, aLo.x + bLo.x);
            lo.y = fmaf(e1, sLo.y, aLo.y + bLo.y);
            lo.z = fmaf(e1, sLo.z, aLo.z + bLo.z);
            lo.w = fmaf(e1, sLo.w, aLo.w + bLo.w);
            hi.x = fmaf(e1, sHi.x, aHi.x + bHi.x);
            hi.y = fmaf(e1, sHi.y, aHi.y + bHi.y);
            hi.z = fmaf(e1, sHi.z, aHi.z + bHi.z);
            hi.w = fmaf(e1, sHi.w, aHi.w + bHi.w);
            const int row = (i & 3) * 16 + (i >> 2);   // sigma(i)
            float4* hp = (float4*)(h_lds + row * HST + e * 8);
            hp[0] = lo;
            hp[1] = hi;
        }
        __syncthreads();
        __builtin_amdgcn_sched_barrier(0);

        // ---- Phase 2: grouped GEMM + ReLU + coalesced full-line stores ----
        float acc[4][4];
#pragma unroll
        for (int m = 0; m < 4; ++m) {
            const float bi = b_lds[g * GOUT + r2 + 12 * m];
#pragma unroll
            for (int nd = 0; nd < 4; ++nd) acc[m][nd] = bi;
        }
#pragma unroll
        for (int ci4 = 0; ci4 < 12; ++ci4) {
            float4 hv[4];
#pragma unroll
            for (int nd = 0; nd < 4; ++nd)    // sigma(4e2+nd) = nd*16 + e2
                hv[nd] = *(const float4*)(h_lds + (nd * 16 + e2) * HST + 4 * ci4);
#pragma unroll
            for (int m = 0; m < 4; ++m) {
                const float4 wm =
                    *(const float4*)(w_lds + (r2 + 12 * m) * WST + 4 * ci4);
#pragma unroll
                for (int nd = 0; nd < 4; ++nd) {
                    acc[m][nd] = fmaf(wm.x, hv[nd].x, acc[m][nd]);
                    acc[m][nd] = fmaf(wm.y, hv[nd].y, acc[m][nd]);
                    acc[m][nd] = fmaf(wm.z, hv[nd].z, acc[m][nd]);
                    acc[m][nd] = fmaf(wm.w, hv[nd].w, acc[m][nd]);
                }
            }
        }
#pragma unroll
        for (int m = 0; m < 4; ++m) {
            const float4 v = make_float4(fmaxf(acc[m][0], 0.0f),
                                         fmaxf(acc[m][1], 0.0f),
                                         fmaxf(acc[m][2], 0.0f),
                                         fmaxf(acc[m][3], 0.0f));
            // 16 consecutive lanes (e2) -> one full 256-B channel row per inst
            *(float4*)(ob + (size_t)(g * GOUT + r2 + 12 * m) * NN + n0 + 4 * e2) = v;
        }
        __syncthreads();   // h_lds/w_lds safe to overwrite next group
    }
}

// ---------------------------------------------------------------------------
extern "C" void kernel_launch(void* const* d_in, const int* in_sizes, int n_in,
                              void* d_out, int out_size, void* d_ws, size_t ws_size,
                              hipStream_t stream) {
    const float* x      = (const float*)d_in[0];
    const int*   edge   = (const int*)  d_in[1];  // edge_index[0] = first half
    const float* weight = (const float*)d_in[2];
    const float* bias   = (const float*)d_in[3];
    const float* eps    = (const float*)d_in[4];
    float*       out    = (float*)d_out;
    __half*      xh     = (__half*)d_ws;          // B*N*192 halfs = 25.2 MB

    dim3 tblk(32, 8);
    dim3 tgrd(NN / 32, CIN / 32, B);
    transpose_h<<<tgrd, tblk, 0, stream>>>(x, xh);

    gin_fused<<<B * (NN / NT), TPB, 0, stream>>>(xh, edge, weight, bias, eps, out);
}